// Round 1
// baseline (601.907 us; speedup 1.0000x reference)
//
#include <hip/hip_runtime.h>
#include <hip/hip_bf16.h>

constexpr int kN = 8192;
constexpr int kD = 128;
constexpr int kV = 3;
constexpr int kNV = kV * kN;

typedef __attribute__((ext_vector_type(8))) short bf16x8;
typedef __attribute__((ext_vector_type(4))) float floatx4;

__device__ __forceinline__ unsigned pack_bf16(float a, float b) {
    unsigned ua = __float_as_uint(a);
    unsigned ub = __float_as_uint(b);
    ua = (ua + 0x7FFFu + ((ua >> 16) & 1u)) >> 16;   // RNE round to bf16
    ub = (ub + 0x7FFFu + ((ub >> 16) & 1u)) >> 16;
    return ua | (ub << 16);
}

// One wave per row. Rows [0,kN): Hc (scale folded 1/T = 2.0). Rows [kN, kN+kV*kN): Hv flat.
__global__ void k_normalize(const float* __restrict__ Hc, const float* __restrict__ Hv,
                            unsigned* __restrict__ HcB, unsigned* __restrict__ HvB) {
    int row  = (blockIdx.x * blockDim.x + threadIdx.x) >> 6;
    int lane = threadIdx.x & 63;
    const float* src;
    unsigned* dst;
    float extra;
    if (row < kN) { src = Hc + (size_t)row * kD; dst = HcB + (size_t)row * (kD / 2); extra = 2.0f; }
    else {
        int r = row - kN;
        src = Hv + (size_t)r * kD; dst = HvB + (size_t)r * (kD / 2); extra = 1.0f;
    }
    float2 x = ((const float2*)src)[lane];
    float ss = x.x * x.x + x.y * x.y;
    ss += __shfl_xor(ss, 1);  ss += __shfl_xor(ss, 2);  ss += __shfl_xor(ss, 4);
    ss += __shfl_xor(ss, 8);  ss += __shfl_xor(ss, 16); ss += __shfl_xor(ss, 32);
    float inv = extra * rsqrtf(fmaxf(ss, 1e-24f));   // matches x / max(||x||, 1e-12)
    dst[lane] = pack_bf16(x.x * inv, x.y * inv);
}

// One wave per (v,n): positive = dot(Hc2[n], Hvn[v,n]) (= sim/T already). atomicAdd -pos/(N*V).
__global__ void k_positive(const unsigned* __restrict__ HcB, const unsigned* __restrict__ HvB,
                           float* __restrict__ out) {
    int row  = (blockIdx.x * blockDim.x + threadIdx.x) >> 6;  // v*kN + n
    int lane = threadIdx.x & 63;
    int w    = threadIdx.x >> 6;
    int n    = row & (kN - 1);
    unsigned a = HcB[(size_t)n * (kD / 2) + lane];
    unsigned b = HvB[(size_t)row * (kD / 2) + lane];
    float dot = __uint_as_float(a << 16) * __uint_as_float(b << 16)
              + __uint_as_float(a & 0xFFFF0000u) * __uint_as_float(b & 0xFFFF0000u);
    dot += __shfl_xor(dot, 1);  dot += __shfl_xor(dot, 2);  dot += __shfl_xor(dot, 4);
    dot += __shfl_xor(dot, 8);  dot += __shfl_xor(dot, 16); dot += __shfl_xor(dot, 32);
    __shared__ float acc4[4];
    if (lane == 0) acc4[w] = dot;
    __syncthreads();
    if (threadIdx.x == 0)
        atomicAdd(out, (acc4[0] + acc4[1] + acc4[2] + acc4[3]) * (-1.0f / kNV));
}

// Main: block = 4 waves; wave owns 16 m-rows (A-frags for 3 views persistent in regs).
// Loop over n-tiles: MFMA sim tile (16m x 16n), exp * (1-S), reduce over m, atomic into denom[v][n].
__launch_bounds__(256, 2)
__global__ void k_main(const unsigned* __restrict__ HcB, const unsigned* __restrict__ HvB,
                       const float* __restrict__ S, float* __restrict__ denom) {
    __shared__ short tile[16 * 136];       // 272B row stride: 16B-aligned, 2-way bank pattern (free)
    __shared__ float dl[4][3][16];

    const int tid  = threadIdx.x;
    const int w    = tid >> 6;
    const int lane = tid & 63;
    const int col  = lane & 15;            // C col -> n index
    const int quad = lane >> 4;            // C row group -> m
    const int m0w  = blockIdx.x * 64 + w * 16;
    const int nbase = blockIdx.y * 2048;

    // Persistent A fragments: A[m=lane&15][k=quad*8+j], k chunks of 32
    bf16x8 afrag[kV][4];
#pragma unroll
    for (int v = 0; v < kV; ++v) {
        const short* rowp = (const short*)HvB + ((size_t)(v * kN + m0w + col)) * kD;
#pragma unroll
        for (int kk = 0; kk < 4; ++kk)
            afrag[v][kk] = *(const bf16x8*)(rowp + kk * 32 + quad * 8);
    }

    for (int it = 0; it < 128; ++it) {
        const int n0 = nbase + it * 16;
        // Stage Hc2 tile (16 rows x 256B) into LDS, 16B per thread
        {
            int r = tid >> 4, c = tid & 15;
            float4 v4 = *(const float4*)((const short*)HcB + (size_t)(n0 + r) * kD + c * 8);
            *(float4*)(tile + r * 136 + c * 8) = v4;
        }
        __syncthreads();   // S1: tile ready; prior iter's dl reads complete

        bf16x8 bfrag[4];   // B[k=quad*8+j][n=lane&15] == Hc2[n0+col][k]
#pragma unroll
        for (int kk = 0; kk < 4; ++kk)
            bfrag[kk] = *(const bf16x8*)(tile + col * 136 + kk * 32 + quad * 8);

        float4 s4 = *(const float4*)(S + (size_t)(n0 + col) * kN + m0w + quad * 4);
        float w0 = 1.0f - s4.x, w1 = 1.0f - s4.y, w2 = 1.0f - s4.z, w3 = 1.0f - s4.w;

        floatx4 acc[kV];
#pragma unroll
        for (int v = 0; v < kV; ++v) acc[v] = (floatx4){0.f, 0.f, 0.f, 0.f};
#pragma unroll
        for (int kk = 0; kk < 4; ++kk) {
            acc[0] = __builtin_amdgcn_mfma_f32_16x16x32_bf16(afrag[0][kk], bfrag[kk], acc[0], 0, 0, 0);
            acc[1] = __builtin_amdgcn_mfma_f32_16x16x32_bf16(afrag[1][kk], bfrag[kk], acc[1], 0, 0, 0);
            acc[2] = __builtin_amdgcn_mfma_f32_16x16x32_bf16(afrag[2][kk], bfrag[kk], acc[2], 0, 0, 0);
        }

        float pv[kV];
#pragma unroll
        for (int v = 0; v < kV; ++v) {
            // C[row=quad*4+r][col]; row is the m index -> pairs with w0..w3
            float p = w0 * __expf(acc[v][0]) + w1 * __expf(acc[v][1])
                    + w2 * __expf(acc[v][2]) + w3 * __expf(acc[v][3]);
            p += __shfl_xor(p, 16);
            p += __shfl_xor(p, 32);
            pv[v] = p;   // every lane now holds sum over this wave's 16 m
        }
        if (quad == 0) {
            dl[w][0][col] = pv[0];
            dl[w][1][col] = pv[1];
            dl[w][2][col] = pv[2];
        }
        __syncthreads();   // S2: dl ready; all tile reads complete
        if (tid < 48) {
            int v = tid >> 4, c = tid & 15;
            float s = dl[0][v][c] + dl[1][v][c] + dl[2][v][c] + dl[3][v][c];
            atomicAdd(&denom[(size_t)v * kN + n0 + c], s);
        }
        // next iter's dl writes happen after next S1, which readers reach only after reads: safe
    }
}

__global__ void k_final(const float* __restrict__ denom, float* __restrict__ out) {
    int idx  = blockIdx.x * 256 + threadIdx.x;   // 0..kNV-1
    int lane = threadIdx.x & 63;
    int w    = threadIdx.x >> 6;
    float val = logf(fmaxf(denom[idx], 1e-9f));
    val += __shfl_xor(val, 1);  val += __shfl_xor(val, 2);  val += __shfl_xor(val, 4);
    val += __shfl_xor(val, 8);  val += __shfl_xor(val, 16); val += __shfl_xor(val, 32);
    __shared__ float acc4[4];
    if (lane == 0) acc4[w] = val;
    __syncthreads();
    if (threadIdx.x == 0)
        atomicAdd(out, (acc4[0] + acc4[1] + acc4[2] + acc4[3]) * (1.0f / kNV));
}

extern "C" void kernel_launch(void* const* d_in, const int* in_sizes, int n_in,
                              void* d_out, int out_size, void* d_ws, size_t ws_size,
                              hipStream_t stream) {
    const float* Hc = (const float*)d_in[0];   // [N, D] fp32
    const float* S  = (const float*)d_in[1];   // [N, N] fp32
    const float* Hv = (const float*)d_in[2];   // [V, N, D] fp32

    unsigned* HcB  = (unsigned*)d_ws;                      // N*D/2 uints   = 2 MB
    unsigned* HvB  = HcB + (size_t)kN * (kD / 2);          // V*N*D/2 uints = 6 MB
    float*    den  = (float*)(HvB + (size_t)kV * kN * (kD / 2)); // V*N floats = 96 KB
    float*    outF = (float*)d_out;

    hipMemsetAsync(den, 0, (size_t)kNV * sizeof(float), stream);
    hipMemsetAsync(outF, 0, sizeof(float), stream);

    k_normalize<<<dim3((kN + kV * kN) / 4), 256, 0, stream>>>(Hc, Hv, HcB, HvB);
    k_positive<<<dim3(kNV / 4), 256, 0, stream>>>(HcB, HvB, outF);
    k_main<<<dim3(kN / 64, 4), dim3(256), 0, stream>>>(HcB, HvB, S, den);
    k_final<<<dim3(kNV / 256), dim3(256), 0, stream>>>(den, outF);
}

// Round 2
// 466.002 us; speedup vs baseline: 1.2916x; 1.2916x over previous
//
#include <hip/hip_runtime.h>
#include <hip/hip_bf16.h>

constexpr int kN = 8192;
constexpr int kD = 128;
constexpr int kV = 3;
constexpr int kNV = kV * kN;
constexpr int kNChunk = 512;             // n columns per k_main block
constexpr int kIters = kNChunk / 16;     // 32
constexpr int kAccStride = 528;          // 512 + 16: shifts banks per view, keeps <=2-way

typedef __attribute__((ext_vector_type(8))) short bf16x8;
typedef __attribute__((ext_vector_type(4))) float floatx4;

__device__ __forceinline__ unsigned pack_bf16(float a, float b) {
    unsigned ua = __float_as_uint(a);
    unsigned ub = __float_as_uint(b);
    ua = (ua + 0x7FFFu + ((ua >> 16) & 1u)) >> 16;   // RNE round to bf16
    ub = (ub + 0x7FFFu + ((ub >> 16) & 1u)) >> 16;
    return ua | (ub << 16);
}

// One wave per row. Rows [0,kN): Hc (scale 1/T = 2.0 folded). Rows [kN, kN+kV*kN): Hv flat.
__global__ void k_normalize(const float* __restrict__ Hc, const float* __restrict__ Hv,
                            unsigned* __restrict__ HcB, unsigned* __restrict__ HvB) {
    int row  = (blockIdx.x * blockDim.x + threadIdx.x) >> 6;
    int lane = threadIdx.x & 63;
    const float* src;
    unsigned* dst;
    float extra;
    if (row < kN) { src = Hc + (size_t)row * kD; dst = HcB + (size_t)row * (kD / 2); extra = 2.0f; }
    else {
        int r = row - kN;
        src = Hv + (size_t)r * kD; dst = HvB + (size_t)r * (kD / 2); extra = 1.0f;
    }
    float2 x = ((const float2*)src)[lane];
    float ss = x.x * x.x + x.y * x.y;
    ss += __shfl_xor(ss, 1);  ss += __shfl_xor(ss, 2);  ss += __shfl_xor(ss, 4);
    ss += __shfl_xor(ss, 8);  ss += __shfl_xor(ss, 16); ss += __shfl_xor(ss, 32);
    float inv = extra * rsqrtf(fmaxf(ss, 1e-24f));
    dst[lane] = pack_bf16(x.x * inv, x.y * inv);
}

// One wave per (v,n). Raw dot sums scattered into 256 partial slots (no same-address pileup).
__global__ void k_positive(const unsigned* __restrict__ HcB, const unsigned* __restrict__ HvB,
                           float* __restrict__ pos_partial) {
    int row  = (blockIdx.x * blockDim.x + threadIdx.x) >> 6;  // v*kN + n
    int lane = threadIdx.x & 63;
    int w    = threadIdx.x >> 6;
    int n    = row & (kN - 1);
    unsigned a = HcB[(size_t)n * (kD / 2) + lane];
    unsigned b = HvB[(size_t)row * (kD / 2) + lane];
    float dot = __uint_as_float(a << 16) * __uint_as_float(b << 16)
              + __uint_as_float(a & 0xFFFF0000u) * __uint_as_float(b & 0xFFFF0000u);
    dot += __shfl_xor(dot, 1);  dot += __shfl_xor(dot, 2);  dot += __shfl_xor(dot, 4);
    dot += __shfl_xor(dot, 8);  dot += __shfl_xor(dot, 16); dot += __shfl_xor(dot, 32);
    __shared__ float acc4[4];
    if (lane == 0) acc4[w] = dot;
    __syncthreads();
    if (threadIdx.x == 0)
        atomicAdd(&pos_partial[blockIdx.x & 255], acc4[0] + acc4[1] + acc4[2] + acc4[3]);
}

// Barrier-free main loop: wave owns 16 m rows x 3 views (A persistent in regs),
// streams 16-wide n tiles; B frags straight from L2-resident HcB; denom partials
// accumulated via LDS atomics; one barrier + global-atomic flush at block end.
__launch_bounds__(256, 3)
__global__ void k_main(const unsigned* __restrict__ HcB, const unsigned* __restrict__ HvB,
                       const float* __restrict__ S, float* __restrict__ denom) {
    __shared__ float accum[kV * kAccStride];

    const int tid  = threadIdx.x;
    const int w    = tid >> 6;
    const int lane = tid & 63;
    const int col  = lane & 15;
    const int quad = lane >> 4;
    const int m0w  = blockIdx.x * 64 + w * 16;
    const int nbase = blockIdx.y * kNChunk;

    for (int i = tid; i < kV * kAccStride; i += 256) accum[i] = 0.f;

    // Persistent A fragments: A[m=lane&15][k=quad*8+j]
    bf16x8 afrag[kV][4];
#pragma unroll
    for (int v = 0; v < kV; ++v) {
        const short* rowp = (const short*)HvB + ((size_t)(v * kN + m0w + col)) * kD;
#pragma unroll
        for (int kk = 0; kk < 4; ++kk)
            afrag[v][kk] = *(const bf16x8*)(rowp + kk * 32 + quad * 8);
    }
    __syncthreads();

    const short* hc = (const short*)HcB;

    // prefetch iter 0
    bf16x8 bCur[4];
#pragma unroll
    for (int kk = 0; kk < 4; ++kk)
        bCur[kk] = *(const bf16x8*)(hc + (size_t)(nbase + col) * kD + kk * 32 + quad * 8);
    float4 sCur = *(const float4*)(S + (size_t)(nbase + col) * kN + m0w + quad * 4);

    for (int it = 0; it < kIters; ++it) {
        // branch-free prefetch of next tile (last iter re-reads tile 0, discarded)
        int itn = (it + 1 < kIters) ? (it + 1) : 0;
        int n0n = nbase + itn * 16;
        bf16x8 bNxt[4];
#pragma unroll
        for (int kk = 0; kk < 4; ++kk)
            bNxt[kk] = *(const bf16x8*)(hc + (size_t)(n0n + col) * kD + kk * 32 + quad * 8);
        float4 sNxt = *(const float4*)(S + (size_t)(n0n + col) * kN + m0w + quad * 4);

        floatx4 acc0 = {0.f,0.f,0.f,0.f}, acc1 = {0.f,0.f,0.f,0.f}, acc2 = {0.f,0.f,0.f,0.f};
#pragma unroll
        for (int kk = 0; kk < 4; ++kk) {
            acc0 = __builtin_amdgcn_mfma_f32_16x16x32_bf16(afrag[0][kk], bCur[kk], acc0, 0, 0, 0);
            acc1 = __builtin_amdgcn_mfma_f32_16x16x32_bf16(afrag[1][kk], bCur[kk], acc1, 0, 0, 0);
            acc2 = __builtin_amdgcn_mfma_f32_16x16x32_bf16(afrag[2][kk], bCur[kk], acc2, 0, 0, 0);
        }
        float w0 = 1.f - sCur.x, w1 = 1.f - sCur.y, w2 = 1.f - sCur.z, w3 = 1.f - sCur.w;
        float p0 = w0 * __expf(acc0[0]) + w1 * __expf(acc0[1]) + w2 * __expf(acc0[2]) + w3 * __expf(acc0[3]);
        float p1 = w0 * __expf(acc1[0]) + w1 * __expf(acc1[1]) + w2 * __expf(acc1[2]) + w3 * __expf(acc1[3]);
        float p2 = w0 * __expf(acc2[0]) + w1 * __expf(acc2[1]) + w2 * __expf(acc2[2]) + w3 * __expf(acc2[3]);
        p0 += __shfl_xor(p0, 16); p0 += __shfl_xor(p0, 32);
        p1 += __shfl_xor(p1, 16); p1 += __shfl_xor(p1, 32);
        p2 += __shfl_xor(p2, 16); p2 += __shfl_xor(p2, 32);
        float val = (quad == 0) ? p0 : ((quad == 1) ? p1 : p2);
        if (quad < 3)
            atomicAdd(&accum[quad * kAccStride + it * 16 + col], val);
#pragma unroll
        for (int kk = 0; kk < 4; ++kk) bCur[kk] = bNxt[kk];
        sCur = sNxt;
    }
    __syncthreads();
    for (int i = tid; i < kV * kNChunk; i += 256) {
        int v = i / kNChunk, c = i - v * kNChunk;
        atomicAdd(&denom[(size_t)v * kN + nbase + c], accum[v * kAccStride + c]);
    }
}

__global__ void k_final(const float* __restrict__ denom, const float* __restrict__ pos_partial,
                        float* __restrict__ out) {
    int idx  = blockIdx.x * 256 + threadIdx.x;   // 0..kNV-1
    int lane = threadIdx.x & 63;
    int w    = threadIdx.x >> 6;
    float val = logf(fmaxf(denom[idx], 1e-9f));
    if (blockIdx.x == 0) val -= pos_partial[threadIdx.x];   // fold positive term once
    val += __shfl_xor(val, 1);  val += __shfl_xor(val, 2);  val += __shfl_xor(val, 4);
    val += __shfl_xor(val, 8);  val += __shfl_xor(val, 16); val += __shfl_xor(val, 32);
    __shared__ float acc4[4];
    if (lane == 0) acc4[w] = val;
    __syncthreads();
    if (threadIdx.x == 0)
        atomicAdd(out, (acc4[0] + acc4[1] + acc4[2] + acc4[3]) * (1.0f / kNV));
}

extern "C" void kernel_launch(void* const* d_in, const int* in_sizes, int n_in,
                              void* d_out, int out_size, void* d_ws, size_t ws_size,
                              hipStream_t stream) {
    const float* Hc = (const float*)d_in[0];   // [N, D] fp32
    const float* S  = (const float*)d_in[1];   // [N, N] fp32
    const float* Hv = (const float*)d_in[2];   // [V, N, D] fp32

    unsigned* HcB  = (unsigned*)d_ws;                            // 2 MB
    unsigned* HvB  = HcB + (size_t)kN * (kD / 2);                // 6 MB
    float*    den  = (float*)(HvB + (size_t)kV * kN * (kD / 2)); // kNV floats
    float*    posp = den + kNV;                                  // 256 floats
    float*    outF = (float*)d_out;

    hipMemsetAsync(den, 0, ((size_t)kNV + 256) * sizeof(float), stream);
    hipMemsetAsync(outF, 0, sizeof(float), stream);

    k_normalize<<<dim3((kN + kV * kN) / 4), 256, 0, stream>>>(Hc, Hv, HcB, HvB);
    k_positive<<<dim3(kNV / 4), 256, 0, stream>>>(HcB, HvB, posp);
    k_main<<<dim3(kN / 64, kN / kNChunk), dim3(256), 0, stream>>>(HcB, HvB, S, den);
    k_final<<<dim3(kNV / 256), dim3(256), 0, stream>>>(den, posp, outF);
}

// Round 3
// 431.485 us; speedup vs baseline: 1.3950x; 1.0800x over previous
//
#include <hip/hip_runtime.h>
#include <hip/hip_bf16.h>

constexpr int kN = 8192;
constexpr int kD = 128;
constexpr int kV = 3;
constexpr int kNV = kV * kN;
constexpr int kNChunk = 512;             // n columns per k_main block
constexpr int kNTile = 32;               // n per iteration (2 MFMA n-subtiles)
constexpr int kIters = kNChunk / kNTile; // 16
constexpr int kAccStride = 529;          // odd stride: the 3 view-rows land on distinct banks

typedef __attribute__((ext_vector_type(8))) short bf16x8;
typedef __attribute__((ext_vector_type(4))) float floatx4;

__device__ __forceinline__ unsigned pack_bf16(float a, float b) {
    unsigned ua = __float_as_uint(a);
    unsigned ub = __float_as_uint(b);
    ua = (ua + 0x7FFFu + ((ua >> 16) & 1u)) >> 16;   // RNE round to bf16
    ub = (ub + 0x7FFFu + ((ub >> 16) & 1u)) >> 16;
    return ua | (ub << 16);
}

// One wave per row. Rows [0,kN): Hc (scale 1/T = 2.0 folded). Rows [kN, kN+kV*kN): Hv flat.
__global__ void k_normalize(const float* __restrict__ Hc, const float* __restrict__ Hv,
                            unsigned* __restrict__ HcB, unsigned* __restrict__ HvB) {
    int row  = (blockIdx.x * blockDim.x + threadIdx.x) >> 6;
    int lane = threadIdx.x & 63;
    const float* src;
    unsigned* dst;
    float extra;
    if (row < kN) { src = Hc + (size_t)row * kD; dst = HcB + (size_t)row * (kD / 2); extra = 2.0f; }
    else {
        int r = row - kN;
        src = Hv + (size_t)r * kD; dst = HvB + (size_t)r * (kD / 2); extra = 1.0f;
    }
    float2 x = ((const float2*)src)[lane];
    float ss = x.x * x.x + x.y * x.y;
    ss += __shfl_xor(ss, 1);  ss += __shfl_xor(ss, 2);  ss += __shfl_xor(ss, 4);
    ss += __shfl_xor(ss, 8);  ss += __shfl_xor(ss, 16); ss += __shfl_xor(ss, 32);
    float inv = extra * rsqrtf(fmaxf(ss, 1e-24f));
    dst[lane] = pack_bf16(x.x * inv, x.y * inv);
}

// One wave per (v,n). Raw dot sums scattered into 256 partial slots.
__global__ void k_positive(const unsigned* __restrict__ HcB, const unsigned* __restrict__ HvB,
                           float* __restrict__ pos_partial) {
    int row  = (blockIdx.x * blockDim.x + threadIdx.x) >> 6;  // v*kN + n
    int lane = threadIdx.x & 63;
    int w    = threadIdx.x >> 6;
    int n    = row & (kN - 1);
    unsigned a = HcB[(size_t)n * (kD / 2) + lane];
    unsigned b = HvB[(size_t)row * (kD / 2) + lane];
    float dot = __uint_as_float(a << 16) * __uint_as_float(b << 16)
              + __uint_as_float(a & 0xFFFF0000u) * __uint_as_float(b & 0xFFFF0000u);
    dot += __shfl_xor(dot, 1);  dot += __shfl_xor(dot, 2);  dot += __shfl_xor(dot, 4);
    dot += __shfl_xor(dot, 8);  dot += __shfl_xor(dot, 16); dot += __shfl_xor(dot, 32);
    __shared__ float acc4[4];
    if (lane == 0) acc4[w] = dot;
    __syncthreads();
    if (threadIdx.x == 0)
        atomicAdd(&pos_partial[blockIdx.x & 255], acc4[0] + acc4[1] + acc4[2] + acc4[3]);
}

// Double-buffered LDS pipeline. Per iter: coalesced global stage of S tile (32n x 64m)
// + Hc tile (32n x 128 bf16), MFMA from LDS, exp*(1-S), LDS-atomic denom partials.
// One barrier per iter; flush once at block end.
__launch_bounds__(256, 3)
__global__ void k_main(const unsigned* __restrict__ HcB, const unsigned* __restrict__ HvB,
                       const float* __restrict__ S, float* __restrict__ denom) {
    __shared__ float Stile[2][kNTile * 68];    // 68-dword row stride (64 + 4 pad, 16B aligned)
    __shared__ short Htile[2][kNTile * 136];   // 136-short row stride (272B, 16B aligned)
    __shared__ float accum[kV * kAccStride];

    const int tid  = threadIdx.x;
    const int w    = tid >> 6;
    const int lane = tid & 63;
    const int col  = lane & 15;
    const int quad = lane >> 4;
    const int m0b  = blockIdx.x * 64;
    const int m0w  = m0b + w * 16;
    const int nbase = blockIdx.y * kNChunk;
    const int sr = tid >> 4;      // staging row 0..15 (and +16)
    const int sc = tid & 15;      // staging 16B chunk

    for (int i = tid; i < kV * kAccStride; i += 256) accum[i] = 0.f;

    // Persistent A fragments: A[m=lane&15][k=quad*8+j]
    bf16x8 afrag[kV][4];
#pragma unroll
    for (int v = 0; v < kV; ++v) {
        const short* rowp = (const short*)HvB + ((size_t)(v * kN + m0w + col)) * kD;
#pragma unroll
        for (int kk = 0; kk < 4; ++kk)
            afrag[v][kk] = *(const bf16x8*)(rowp + kk * 32 + quad * 8);
    }

    const short* hc = (const short*)HcB;

    // preload tile 0
    {
        int n0 = nbase;
        float4 sa = *(const float4*)(S + (size_t)(n0 + sr) * kN + m0b + sc * 4);
        float4 sb = *(const float4*)(S + (size_t)(n0 + sr + 16) * kN + m0b + sc * 4);
        float4 ha = *(const float4*)(hc + (size_t)(n0 + sr) * kD + sc * 8);
        float4 hb = *(const float4*)(hc + (size_t)(n0 + sr + 16) * kD + sc * 8);
        *(float4*)&Stile[0][sr * 68 + sc * 4]        = sa;
        *(float4*)&Stile[0][(sr + 16) * 68 + sc * 4] = sb;
        *(float4*)&Htile[0][sr * 136 + sc * 8]        = ha;
        *(float4*)&Htile[0][(sr + 16) * 136 + sc * 8] = hb;
    }
    __syncthreads();

    for (int it = 0; it < kIters; ++it) {
        // issue next tile's coalesced global loads (clamped re-read on last iter; L2-hot, harmless)
        int itn = (it + 1 < kIters) ? it + 1 : it;
        int n0n = nbase + itn * kNTile;
        float4 sa = *(const float4*)(S + (size_t)(n0n + sr) * kN + m0b + sc * 4);
        float4 sb = *(const float4*)(S + (size_t)(n0n + sr + 16) * kN + m0b + sc * 4);
        float4 ha = *(const float4*)(hc + (size_t)(n0n + sr) * kD + sc * 8);
        float4 hb = *(const float4*)(hc + (size_t)(n0n + sr + 16) * kD + sc * 8);

        const int cur = it & 1;
#pragma unroll
        for (int sub = 0; sub < 2; ++sub) {
            const int nrow = sub * 16 + col;
            bf16x8 bfrag[4];
#pragma unroll
            for (int kk = 0; kk < 4; ++kk)
                bfrag[kk] = *(const bf16x8*)&Htile[cur][nrow * 136 + kk * 32 + quad * 8];
            float4 s4 = *(const float4*)&Stile[cur][nrow * 68 + w * 16 + quad * 4];

            floatx4 acc0 = {0.f,0.f,0.f,0.f}, acc1 = {0.f,0.f,0.f,0.f}, acc2 = {0.f,0.f,0.f,0.f};
#pragma unroll
            for (int kk = 0; kk < 4; ++kk) {
                acc0 = __builtin_amdgcn_mfma_f32_16x16x32_bf16(afrag[0][kk], bfrag[kk], acc0, 0, 0, 0);
                acc1 = __builtin_amdgcn_mfma_f32_16x16x32_bf16(afrag[1][kk], bfrag[kk], acc1, 0, 0, 0);
                acc2 = __builtin_amdgcn_mfma_f32_16x16x32_bf16(afrag[2][kk], bfrag[kk], acc2, 0, 0, 0);
            }
            float w0 = 1.f - s4.x, w1 = 1.f - s4.y, w2 = 1.f - s4.z, w3 = 1.f - s4.w;
            float p0 = w0 * __expf(acc0[0]) + w1 * __expf(acc0[1]) + w2 * __expf(acc0[2]) + w3 * __expf(acc0[3]);
            float p1 = w0 * __expf(acc1[0]) + w1 * __expf(acc1[1]) + w2 * __expf(acc1[2]) + w3 * __expf(acc1[3]);
            float p2 = w0 * __expf(acc2[0]) + w1 * __expf(acc2[1]) + w2 * __expf(acc2[2]) + w3 * __expf(acc2[3]);
            p0 += __shfl_xor(p0, 16); p0 += __shfl_xor(p0, 32);
            p1 += __shfl_xor(p1, 16); p1 += __shfl_xor(p1, 32);
            p2 += __shfl_xor(p2, 16); p2 += __shfl_xor(p2, 32);
            float val = (quad == 0) ? p0 : ((quad == 1) ? p1 : p2);
            if (quad < 3)
                atomicAdd(&accum[quad * kAccStride + it * kNTile + sub * 16 + col], val);
        }

        const int nxt = cur ^ 1;
        *(float4*)&Stile[nxt][sr * 68 + sc * 4]        = sa;
        *(float4*)&Stile[nxt][(sr + 16) * 68 + sc * 4] = sb;
        *(float4*)&Htile[nxt][sr * 136 + sc * 8]        = ha;
        *(float4*)&Htile[nxt][(sr + 16) * 136 + sc * 8] = hb;
        __syncthreads();
    }

    for (int i = tid; i < kV * kNChunk; i += 256) {
        int v = i >> 9, c = i & (kNChunk - 1);
        atomicAdd(&denom[(size_t)v * kN + nbase + c], accum[v * kAccStride + c]);
    }
}

__global__ void k_final(const float* __restrict__ denom, const float* __restrict__ pos_partial,
                        float* __restrict__ out) {
    int idx  = blockIdx.x * 256 + threadIdx.x;   // 0..kNV-1
    int lane = threadIdx.x & 63;
    int w    = threadIdx.x >> 6;
    float val = logf(fmaxf(denom[idx], 1e-9f));
    if (blockIdx.x == 0) val -= pos_partial[threadIdx.x];   // fold positive term once
    val += __shfl_xor(val, 1);  val += __shfl_xor(val, 2);  val += __shfl_xor(val, 4);
    val += __shfl_xor(val, 8);  val += __shfl_xor(val, 16); val += __shfl_xor(val, 32);
    __shared__ float acc4[4];
    if (lane == 0) acc4[w] = val;
    __syncthreads();
    if (threadIdx.x == 0)
        atomicAdd(out, (acc4[0] + acc4[1] + acc4[2] + acc4[3]) * (1.0f / kNV));
}

extern "C" void kernel_launch(void* const* d_in, const int* in_sizes, int n_in,
                              void* d_out, int out_size, void* d_ws, size_t ws_size,
                              hipStream_t stream) {
    const float* Hc = (const float*)d_in[0];   // [N, D] fp32
    const float* S  = (const float*)d_in[1];   // [N, N] fp32
    const float* Hv = (const float*)d_in[2];   // [V, N, D] fp32

    unsigned* HcB  = (unsigned*)d_ws;                            // 2 MB
    unsigned* HvB  = HcB + (size_t)kN * (kD / 2);                // 6 MB
    float*    den  = (float*)(HvB + (size_t)kV * kN * (kD / 2)); // kNV floats
    float*    posp = den + kNV;                                  // 256 floats
    float*    outF = (float*)d_out;

    hipMemsetAsync(den, 0, ((size_t)kNV + 256) * sizeof(float), stream);
    hipMemsetAsync(outF, 0, sizeof(float), stream);

    k_normalize<<<dim3((kN + kV * kN) / 4), 256, 0, stream>>>(Hc, Hv, HcB, HvB);
    k_positive<<<dim3(kNV / 4), 256, 0, stream>>>(HcB, HvB, posp);
    k_main<<<dim3(kN / 64, kN / kNChunk), dim3(256), 0, stream>>>(HcB, HvB, S, den);
    k_final<<<dim3(kNV / 256), dim3(256), 0, stream>>>(den, posp, outF);
}